// Round 5
// baseline (203.101 us; speedup 1.0000x reference)
//
#include <hip/hip_runtime.h>
#include <hip/hip_bf16.h>

// CACE message passing, fused. MAX_L=3 -> NL=20, N_RBF=8, RB=8, K=3 -> C=9,
// NB=5, CUTOFF=5.5, T_MP=1, MP_NORM=0.2, N=2000, E=50000. fp32 I/O.
// Round 5: node kernels process NPB=4 nodes per block (500 blocks, not 2000) —
// r3/r4 showed ~44us per node kernel invariant to inner-loop structure, i.e.
// per-workgroup dispatch/prologue overhead dominates (waves ~87% idle).
// edata row (64 floats): [0:8] g, [8:16] fr, [16:36] ang, [36:45] enc.
// A-gather via bf16 b-pair planes [bp][n][lc] (1.44 MB/plane, L2-resident).

#define CUTF 5.5f
#define MPNORM 0.2f
#define NPB 4

__constant__ int   d_DEGS[20]  = {0,1,1,1,2,2,2,2,2,2,3,3,3,3,3,3,3,3,3,3};
__constant__ float d_MULTI[20] = {1,1,1,1,1,2,2,1,2,1,1,3,3,3,6,3,1,3,3,1};

__global__ void k_edge(const float* __restrict__ pos,
                       const float* __restrict__ shifts,
                       const float* __restrict__ Wemb,
                       const float* __restrict__ War,
                       const int* __restrict__ species,
                       const int* __restrict__ eidx,
                       float* __restrict__ edata,
                       int* __restrict__ counts,
                       int E) {
  __shared__ float war_s[64];
  int t = threadIdx.x;
  if (t < 64) war_s[t] = War[t];
  __syncthreads();
  int e = blockIdx.x * blockDim.x + t;
  if (e >= E) return;
  int s  = eidx[e];
  int rI = eidx[E + e];
  float vx = pos[rI*3+0] - pos[s*3+0] + shifts[e*3+0];
  float vy = pos[rI*3+1] - pos[s*3+1] + shifts[e*3+1];
  float vz = pos[rI*3+2] - pos[s*3+2] + shifts[e*3+2];
  float len = sqrtf(vx*vx + vy*vy + vz*vz);
  float inv = 1.0f / (len + 1e-9f);
  float ux = vx*inv, uy = vy*inv, uz = vz*inv;
  float uu = len * (1.0f/CUTF);
  float u2 = uu*uu, u6 = u2*u2*u2;
  float fcut = (uu < 1.0f) ? (1.0f - 28.0f*u6 + 48.0f*u6*uu - 21.0f*u6*u2) : 0.0f;
  float x = 3.14159265358979f * uu;
  float sn = sinf(x), c2 = 2.0f*cosf(x), snm1 = 0.0f;
  float pref = sqrtf(2.0f/CUTF) / (len + 1e-20f);
  float rad[8];
  float v[48];
  #pragma unroll
  for (int k = 0; k < 8; k++) {
    rad[k] = pref * sn;
    v[k]   = rad[k] * fcut;           // g
    float nxt = c2*sn - snm1; snm1 = sn; sn = nxt;
  }
  #pragma unroll
  for (int b = 0; b < 8; b++) {       // fr = (rad @ W_ar) * fcut
    float a = 0.0f;
    #pragma unroll
    for (int k = 0; k < 8; k++) a += rad[k] * war_s[k*8+b];
    v[8+b] = a * fcut;
  }
  float px2 = ux*ux, py2 = uy*uy, pz2 = uz*uz;
  v[16] = 1.0f; v[17] = ux;     v[18] = uy;     v[19] = uz;
  v[20] = px2;  v[21] = ux*uy;  v[22] = ux*uz;  v[23] = py2;
  v[24] = uy*uz;v[25] = pz2;
  v[26] = px2*ux; v[27] = px2*uy; v[28] = px2*uz; v[29] = ux*py2;
  v[30] = ux*uy*uz; v[31] = ux*pz2; v[32] = py2*uy; v[33] = py2*uz;
  v[34] = uy*pz2; v[35] = pz2*uz;
  int zs = species[s], zr = species[rI];
  float es0 = Wemb[zs*3+0], es1 = Wemb[zs*3+1], es2 = Wemb[zs*3+2];
  float er0 = Wemb[zr*3+0], er1 = Wemb[zr*3+1], er2 = Wemb[zr*3+2];
  v[36] = es0*er0; v[37] = es0*er1; v[38] = es0*er2;
  v[39] = es1*er0; v[40] = es1*er1; v[41] = es1*er2;
  v[42] = es2*er0; v[43] = es2*er1; v[44] = es2*er2;
  v[45] = 0.0f; v[46] = 0.0f; v[47] = 0.0f;
  float4* eb4 = reinterpret_cast<float4*>(edata + (size_t)e * 64);
  #pragma unroll
  for (int w = 0; w < 12; w++)
    eb4[w] = make_float4(v[4*w], v[4*w+1], v[4*w+2], v[4*w+3]);
  atomicAdd(&counts[rI], 1);
}

// ---------------- exclusive scan of counts (N<=2048, one block of 256) -------
__global__ void k_scan(const int* __restrict__ counts, int* __restrict__ offs, int N) {
  __shared__ int part[256];
  int t = threadIdx.x;
  int local[8]; int sum = 0;
  #pragma unroll
  for (int i = 0; i < 8; i++) {
    int idx = t*8 + i;
    int v = (idx < N) ? counts[idx] : 0;
    local[i] = sum; sum += v;
  }
  part[t] = sum; __syncthreads();
  for (int d = 1; d < 256; d <<= 1) {
    int add = (t >= d) ? part[t-d] : 0;
    __syncthreads();
    part[t] += add;
    __syncthreads();
  }
  int excl = part[t] - sum;
  #pragma unroll
  for (int i = 0; i < 8; i++) {
    int idx = t*8 + i;
    if (idx < N) offs[idx] = excl + local[i];
  }
  if (t == 255) offs[N] = part[255];
}

__global__ void k_fill(const int* __restrict__ eidx, const int* __restrict__ offs,
                       int* __restrict__ cursor, int* __restrict__ order, int E) {
  int e = blockIdx.x * blockDim.x + threadIdx.x;
  if (e >= E) return;
  int rI = eidx[E + e];
  int slot = atomicAdd(&cursor[rI], 1);
  order[offs[rI] + slot] = e;
}

// ---------------- per-node phase 1: A, Abf2, chi, B0 (NPB nodes per block) ---
__global__ __launch_bounds__(192) void k_nodeA(
    const float* __restrict__ edata, const int* __restrict__ order,
    const int* __restrict__ offs,
    const float* __restrict__ Wrad, const float* __restrict__ Wchi,
    float* __restrict__ A, unsigned int* __restrict__ Abf2,
    float* __restrict__ chi, float* __restrict__ B0, int N) {
  __shared__ float wr_s[288];        // [deg][r][b], deg stride 72
  __shared__ float wchi_s[40];       // [b][k]
  __shared__ float Bsh[360];         // [b][k][c] = b*45 + k*9 + c
  int t = threadIdx.x;
  for (int i = t; i < 256; i += 192) { int d = i >> 6, rm = i & 63; wr_s[d*72+rm] = Wrad[i]; }
  for (int i = t; i < 40;  i += 192) wchi_s[i] = Wchi[i];
  int l = t / 9, c = t - l*9;
  bool act = t < 180;
  int ll = act ? l : 0, cc = act ? c : 0;
  int deg = act ? d_DEGS[ll] : 0;
  float mlt = act ? d_MULTI[ll] : 0.0f;
  const float* wp = &wr_s[deg*72];

  for (int k0 = 0; k0 < NPB; k0++) {
    int n = blockIdx.x * NPB + k0;
    if (n >= N) break;
    __syncthreads();                 // Bsh readers of prev node done; weights visible
    for (int i = t; i < 360; i += 192) Bsh[i] = 0.0f;
    float acc[8];
    #pragma unroll
    for (int r = 0; r < 8; r++) acc[r] = 0.0f;
    int start = offs[n], end = offs[n+1];
    #pragma unroll 4
    for (int j = start; j < end; j++) {
      int e = order[j];                              // uniform
      const float* row = edata + (size_t)e * 64;
      float p = row[16+ll] * row[36+cc];             // per-lane (L1)
      #pragma unroll
      for (int r = 0; r < 8; r++) acc[r] += row[r] * p;
    }
    __syncthreads();                 // Bsh zeros visible
    float Ab[8];
    #pragma unroll
    for (int b = 0; b < 8; b++) {
      float a = 0.0f;
      #pragma unroll
      for (int r = 0; r < 8; r++) a += acc[r] * wp[r*8+b];
      Ab[b] = a;
    }
    if (act) {
      #pragma unroll
      for (int b = 0; b < 8; b++) A[(size_t)n*1440 + t*8 + b] = Ab[b];
      #pragma unroll
      for (int bp = 0; bp < 4; bp++) {
        __hip_bfloat16 blo = __float2bfloat16(Ab[2*bp]);
        __hip_bfloat16 bhi = __float2bfloat16(Ab[2*bp+1]);
        unsigned int pr = (unsigned int)(*reinterpret_cast<unsigned short*>(&blo))
                        | ((unsigned int)(*reinterpret_cast<unsigned short*>(&bhi)) << 16);
        Abf2[(size_t)bp*N*180 + (size_t)n*180 + t] = pr;
      }
      if (l == 0) {
        #pragma unroll
        for (int b = 0; b < 8; b++) Bsh[b*45 + c] = Ab[b];
      }
      int kk = 1 + deg;
      #pragma unroll
      for (int b = 0; b < 8; b++) atomicAdd(&Bsh[b*45 + kk*9 + c], mlt*Ab[b]*Ab[b]);
    }
    __syncthreads();
    if (t < 9) {
      float s = 0.0f;
      for (int b = 0; b < 8; b++)
        #pragma unroll
        for (int kq = 0; kq < 5; kq++) s += Bsh[b*45 + kq*9 + t] * wchi_s[b*5 + kq];
      chi[n*9 + t] = s;
    }
    for (int i = t; i < 360; i += 192)
      B0[(size_t)n*360 + i] = Bsh[i];     // contiguous, coalesced
  }
}

// ---------------- per-node phase 2: A' = (A_ar+A_bchi)*norm + mem; out -------
__global__ __launch_bounds__(192) void k_node2(
    const float* __restrict__ edata, const int* __restrict__ order,
    const int* __restrict__ offs, const int* __restrict__ eidx,
    const float* __restrict__ Wrad, const float* __restrict__ Wmem,
    const float* __restrict__ A, const unsigned int* __restrict__ Abf2,
    const float* __restrict__ chi, const float* __restrict__ B0,
    float* __restrict__ out, int N) {
  __shared__ float wr_s[288], wm_s[288];
  __shared__ float Bsh[360];
  int t = threadIdx.x;
  for (int i = t; i < 256; i += 192) {
    int d = i >> 6, rm = i & 63;
    wr_s[d*72+rm] = Wrad[i];
    wm_s[d*72+rm] = Wmem[i];
  }
  int l = t / 9, c = t - l*9;
  bool act = t < 180;
  int ll = act ? l : 0, cc = act ? c : 0;
  int tt = act ? t : 0;
  int deg = act ? d_DEGS[ll] : 0;
  float mlt = act ? d_MULTI[ll] : 0.0f;
  const float* wrp = &wr_s[deg*72];
  const float* wmp = &wm_s[deg*72];
  size_t plane = (size_t)N * 180;

  for (int k0 = 0; k0 < NPB; k0++) {
    int n = blockIdx.x * NPB + k0;
    if (n >= N) break;
    __syncthreads();
    for (int i = t; i < 360; i += 192) Bsh[i] = 0.0f;
    float Sacc[8], ARacc[8];
    #pragma unroll
    for (int r = 0; r < 8; r++) { Sacc[r] = 0.0f; ARacc[r] = 0.0f; }
    int start = offs[n], end = offs[n+1];
    #pragma unroll 4
    for (int j = start; j < end; j++) {
      int e = order[j];                               // uniform
      const float* row = edata + (size_t)e * 64;
      int snd = eidx[e];                              // uniform
      float ch = chi[snd*9 + cc];                     // per-lane
      float pch = row[16+ll] * row[36+cc] * ch;
      #pragma unroll
      for (int r = 0; r < 8; r++) Sacc[r] += row[r] * pch;
      const unsigned int* gp = Abf2 + (size_t)snd*180 + tt;   // coalesced 4B/lane
      unsigned int q0 = gp[0];
      unsigned int q1 = gp[plane];
      unsigned int q2 = gp[2*plane];
      unsigned int q3 = gp[3*plane];
      float a0 = __uint_as_float(q0 << 16), a1 = __uint_as_float(q0 & 0xffff0000u);
      float a2 = __uint_as_float(q1 << 16), a3 = __uint_as_float(q1 & 0xffff0000u);
      float a4 = __uint_as_float(q2 << 16), a5 = __uint_as_float(q2 & 0xffff0000u);
      float a6 = __uint_as_float(q3 << 16), a7 = __uint_as_float(q3 & 0xffff0000u);
      ARacc[0] += a0*row[8];  ARacc[1] += a1*row[9];
      ARacc[2] += a2*row[10]; ARacc[3] += a3*row[11];
      ARacc[4] += a4*row[12]; ARacc[5] += a5*row[13];
      ARacc[6] += a6*row[14]; ARacc[7] += a7*row[15];
    }
    __syncthreads();                 // Bsh zeros visible
    if (act) {
      const float* aop = A + (size_t)n*1440 + t*8;
      float aown[8];
      #pragma unroll
      for (int r = 0; r < 8; r++) aown[r] = aop[r];
      float newA[8];
      #pragma unroll
      for (int b = 0; b < 8; b++) {
        float mem = 0.0f, ab = 0.0f;
        #pragma unroll
        for (int r = 0; r < 8; r++) { mem += aown[r]*wmp[r*8+b]; ab += Sacc[r]*wrp[r*8+b]; }
        newA[b] = (ARacc[b] + ab)*MPNORM + mem;
      }
      if (l == 0) {
        #pragma unroll
        for (int b = 0; b < 8; b++) Bsh[b*45 + c] = newA[b];
      }
      int kk = 1 + deg;
      #pragma unroll
      for (int b = 0; b < 8; b++) atomicAdd(&Bsh[b*45 + kk*9 + c], mlt*newA[b]*newA[b]);
    }
    __syncthreads();
    float2* out2 = reinterpret_cast<float2*>(out);
    for (int i = t; i < 360; i += 192) {
      float2 pk; pk.x = B0[(size_t)n*360 + i]; pk.y = Bsh[i];
      out2[(size_t)n*360 + i] = pk;            // coalesced 8B stores
    }
  }
}

extern "C" void kernel_launch(void* const* d_in, const int* in_sizes, int n_in,
                              void* d_out, int out_size, void* d_ws, size_t ws_size,
                              hipStream_t stream) {
  const float* pos    = (const float*)d_in[0];
  const float* shifts = (const float*)d_in[1];
  const float* Wemb   = (const float*)d_in[2];
  const float* Wrad   = (const float*)d_in[3];
  const float* Wmem   = (const float*)d_in[4];
  const float* War    = (const float*)d_in[5];
  const float* Wchi   = (const float*)d_in[6];
  const int* species = (const int*)d_in[7];
  const int* eidx    = (const int*)d_in[8];
  float* out = (float*)d_out;
  int N = in_sizes[7];
  int E = in_sizes[8] / 2;

  char* base = (char*)d_ws;
  size_t off = 0;
  float* edata = (float*)(base + off); off += (size_t)E*64*4;          // 12.8 MB
  float* A     = (float*)(base + off); off += (size_t)N*1440*4;        // 11.52 MB
  unsigned int* Abf2 = (unsigned int*)(base + off); off += (size_t)N*180*4*4; // 5.76 MB
  float* chi   = (float*)(base + off); off += (size_t)N*9*4;
  float* B0    = (float*)(base + off); off += (size_t)N*360*4;         // 2.88 MB
  int* counts  = (int*)(base + off);   off += (size_t)N*4;
  int* cursor  = (int*)(base + off);   off += (size_t)N*4;
  int* offs    = (int*)(base + off);   off += (((size_t)(N+1)*4) + 15) & ~(size_t)15;
  int* order   = (int*)(base + off);   off += (size_t)E*4;

  hipMemsetAsync(counts, 0, (size_t)N*2*4, stream);  // counts + cursor (adjacent)
  int eb = (E + 255) / 256;
  int nb = (N + NPB - 1) / NPB;
  k_edge<<<eb, 256, 0, stream>>>(pos, shifts, Wemb, War, species, eidx, edata, counts, E);
  k_scan<<<1, 256, 0, stream>>>(counts, offs, N);
  k_fill<<<eb, 256, 0, stream>>>(eidx, offs, cursor, order, E);
  k_nodeA<<<nb, 192, 0, stream>>>(edata, order, offs, Wrad, Wchi, A, Abf2, chi, B0, N);
  k_node2<<<nb, 192, 0, stream>>>(edata, order, offs, eidx, Wrad, Wmem, A, Abf2, chi, B0, out, N);
}

// Round 6
// 169.001 us; speedup vs baseline: 1.2018x; 1.2018x over previous
//
#include <hip/hip_runtime.h>
#include <hip/hip_bf16.h>

// CACE message passing, fused. MAX_L=3 -> NL=20, N_RBF=8, RB=8, K=3 -> C=9,
// NB=5, CUTOFF=5.5, T_MP=1, MP_NORM=0.2, N=2000, E=50000. fp32 I/O.
// Round 6: edge rows are written CSR-SORTED by recv (k_count/k_scan first,
// then k_edge scatters to its final slot). Node kernels thus read edge data at
// affine, sequential addresses -> no pointer-chase (r5 post-mortem: ~1000 cyc
// per edge = chained order->row->snd->gather latency at IC ~600-900 cyc).
// Only depth-1 chain left: snd -> chi/Abf2 gather, pipelined by unroll 4.
// Row (48 floats): [0:8] g, [8:16] fr, [16:36] ang, [36:45] enc, [45:48] pad.
// A-gather via bf16 b-pair planes [bp][n][lc] (1.44 MB/plane, L2-friendly).

#define CUTF 5.5f
#define MPNORM 0.2f

__constant__ int   d_DEGS[20]  = {0,1,1,1,2,2,2,2,2,2,3,3,3,3,3,3,3,3,3,3};
__constant__ float d_MULTI[20] = {1,1,1,1,1,2,2,1,2,1,1,3,3,3,6,3,1,3,3,1};

__global__ void k_count(const int* __restrict__ eidx, int* __restrict__ counts, int E) {
  int e = blockIdx.x * blockDim.x + threadIdx.x;
  if (e < E) atomicAdd(&counts[eidx[E + e]], 1);
}

// ---------------- exclusive scan of counts (N<=2048, one block of 256) -------
__global__ void k_scan(const int* __restrict__ counts, int* __restrict__ offs, int N) {
  __shared__ int part[256];
  int t = threadIdx.x;
  int local[8]; int sum = 0;
  #pragma unroll
  for (int i = 0; i < 8; i++) {
    int idx = t*8 + i;
    int v = (idx < N) ? counts[idx] : 0;
    local[i] = sum; sum += v;
  }
  part[t] = sum; __syncthreads();
  for (int d = 1; d < 256; d <<= 1) {
    int add = (t >= d) ? part[t-d] : 0;
    __syncthreads();
    part[t] += add;
    __syncthreads();
  }
  int excl = part[t] - sum;
  #pragma unroll
  for (int i = 0; i < 8; i++) {
    int idx = t*8 + i;
    if (idx < N) offs[idx] = excl + local[i];
  }
  if (t == 255) offs[N] = part[255];
}

// ------------- per-edge compute, scattered directly into CSR slot ------------
__global__ void k_edge(const float* __restrict__ pos,
                       const float* __restrict__ shifts,
                       const float* __restrict__ Wemb,
                       const float* __restrict__ War,
                       const int* __restrict__ species,
                       const int* __restrict__ eidx,
                       const int* __restrict__ offs,
                       int* __restrict__ cursor,
                       float* __restrict__ edata,
                       int* __restrict__ esend,
                       int E) {
  __shared__ float war_s[64];
  int t = threadIdx.x;
  if (t < 64) war_s[t] = War[t];
  __syncthreads();
  int e = blockIdx.x * blockDim.x + t;
  if (e >= E) return;
  int s  = eidx[e];
  int rI = eidx[E + e];
  float vx = pos[rI*3+0] - pos[s*3+0] + shifts[e*3+0];
  float vy = pos[rI*3+1] - pos[s*3+1] + shifts[e*3+1];
  float vz = pos[rI*3+2] - pos[s*3+2] + shifts[e*3+2];
  float len = sqrtf(vx*vx + vy*vy + vz*vz);
  float inv = 1.0f / (len + 1e-9f);
  float ux = vx*inv, uy = vy*inv, uz = vz*inv;
  float uu = len * (1.0f/CUTF);
  float u2 = uu*uu, u6 = u2*u2*u2;
  float fcut = (uu < 1.0f) ? (1.0f - 28.0f*u6 + 48.0f*u6*uu - 21.0f*u6*u2) : 0.0f;
  float x = 3.14159265358979f * uu;
  float sn = sinf(x), c2 = 2.0f*cosf(x), snm1 = 0.0f;
  float pref = sqrtf(2.0f/CUTF) / (len + 1e-20f);
  float rad[8];
  float v[48];
  #pragma unroll
  for (int k = 0; k < 8; k++) {
    rad[k] = pref * sn;
    v[k]   = rad[k] * fcut;           // g
    float nxt = c2*sn - snm1; snm1 = sn; sn = nxt;
  }
  #pragma unroll
  for (int b = 0; b < 8; b++) {       // fr = (rad @ W_ar) * fcut
    float a = 0.0f;
    #pragma unroll
    for (int k = 0; k < 8; k++) a += rad[k] * war_s[k*8+b];
    v[8+b] = a * fcut;
  }
  float px2 = ux*ux, py2 = uy*uy, pz2 = uz*uz;
  v[16] = 1.0f; v[17] = ux;     v[18] = uy;     v[19] = uz;
  v[20] = px2;  v[21] = ux*uy;  v[22] = ux*uz;  v[23] = py2;
  v[24] = uy*uz;v[25] = pz2;
  v[26] = px2*ux; v[27] = px2*uy; v[28] = px2*uz; v[29] = ux*py2;
  v[30] = ux*uy*uz; v[31] = ux*pz2; v[32] = py2*uy; v[33] = py2*uz;
  v[34] = uy*pz2; v[35] = pz2*uz;
  int zs = species[s], zr = species[rI];
  float es0 = Wemb[zs*3+0], es1 = Wemb[zs*3+1], es2 = Wemb[zs*3+2];
  float er0 = Wemb[zr*3+0], er1 = Wemb[zr*3+1], er2 = Wemb[zr*3+2];
  v[36] = es0*er0; v[37] = es0*er1; v[38] = es0*er2;
  v[39] = es1*er0; v[40] = es1*er1; v[41] = es1*er2;
  v[42] = es2*er0; v[43] = es2*er1; v[44] = es2*er2;
  v[45] = 0.0f; v[46] = 0.0f; v[47] = 0.0f;
  int slot = atomicAdd(&cursor[rI], 1);
  int dst = offs[rI] + slot;
  float4* eb4 = reinterpret_cast<float4*>(edata + (size_t)dst * 48);
  #pragma unroll
  for (int w = 0; w < 12; w++)
    eb4[w] = make_float4(v[4*w], v[4*w+1], v[4*w+2], v[4*w+3]);
  esend[dst] = s;
}

// ---------------- per-node phase 1: A, Abf2, chi, B0 -------------------------
// 1 block/node, 192 threads; thread t<180 owns (l=t/9, c=t%9), 8 r/b in regs.
__global__ __launch_bounds__(192) void k_nodeA(
    const float* __restrict__ edata, const int* __restrict__ offs,
    const float* __restrict__ Wrad, const float* __restrict__ Wchi,
    float* __restrict__ A, unsigned int* __restrict__ Abf2,
    float* __restrict__ chi, float* __restrict__ B0, int N) {
  __shared__ float wr_s[288];        // [deg][r][b], deg stride 72
  __shared__ float wchi_s[40];       // [b][k]
  __shared__ float Bsh[360];         // [b][k][c] = b*45 + k*9 + c
  int t = threadIdx.x, n = blockIdx.x;
  for (int i = t; i < 256; i += 192) { int d = i >> 6, rm = i & 63; wr_s[d*72+rm] = Wrad[i]; }
  for (int i = t; i < 40;  i += 192) wchi_s[i] = Wchi[i];
  for (int i = t; i < 360; i += 192) Bsh[i] = 0.0f;
  int l = t / 9, c = t - l*9;
  bool act = t < 180;
  int ll = act ? l : 0, cc = act ? c : 0;
  float acc[8];
  #pragma unroll
  for (int r = 0; r < 8; r++) acc[r] = 0.0f;
  int start = offs[n], end = offs[n+1];
  #pragma unroll 4
  for (int j = start; j < end; j++) {
    const float* row = edata + (size_t)j * 48;      // SEQUENTIAL (affine in j)
    float p = row[16+ll] * row[36+cc];              // per-lane, L1
    #pragma unroll
    for (int r = 0; r < 8; r++) acc[r] += row[r] * p;  // uniform s_load
  }
  __syncthreads();   // weights/Bsh zeros visible
  int deg = act ? d_DEGS[ll] : 0;
  const float* wp = &wr_s[deg*72];
  float Ab[8];
  #pragma unroll
  for (int b = 0; b < 8; b++) {
    float a = 0.0f;
    #pragma unroll
    for (int r = 0; r < 8; r++) a += acc[r] * wp[r*8+b];
    Ab[b] = a;
  }
  if (act) {
    #pragma unroll
    for (int b = 0; b < 8; b++) A[(size_t)n*1440 + t*8 + b] = Ab[b];
    #pragma unroll
    for (int bp = 0; bp < 4; bp++) {
      __hip_bfloat16 blo = __float2bfloat16(Ab[2*bp]);
      __hip_bfloat16 bhi = __float2bfloat16(Ab[2*bp+1]);
      unsigned int pr = (unsigned int)(*reinterpret_cast<unsigned short*>(&blo))
                      | ((unsigned int)(*reinterpret_cast<unsigned short*>(&bhi)) << 16);
      Abf2[(size_t)bp*N*180 + (size_t)n*180 + t] = pr;
    }
    if (l == 0) {
      #pragma unroll
      for (int b = 0; b < 8; b++) Bsh[b*45 + c] = Ab[b];
    }
    float mlt = d_MULTI[ll]; int kk = 1 + deg;
    #pragma unroll
    for (int b = 0; b < 8; b++) atomicAdd(&Bsh[b*45 + kk*9 + c], mlt*Ab[b]*Ab[b]);
  }
  __syncthreads();
  if (t < 9) {
    float s = 0.0f;
    for (int b = 0; b < 8; b++)
      #pragma unroll
      for (int kq = 0; kq < 5; kq++) s += Bsh[b*45 + kq*9 + t] * wchi_s[b*5 + kq];
    chi[n*9 + t] = s;
  }
  for (int i = t; i < 360; i += 192)
    B0[(size_t)n*360 + i] = Bsh[i];     // contiguous, coalesced
}

// ---------------- per-node phase 2: A' = (A_ar+A_bchi)*norm + mem; out -------
__global__ __launch_bounds__(192) void k_node2(
    const float* __restrict__ edata, const int* __restrict__ esend,
    const int* __restrict__ offs,
    const float* __restrict__ Wrad, const float* __restrict__ Wmem,
    const float* __restrict__ A, const unsigned int* __restrict__ Abf2,
    const float* __restrict__ chi, const float* __restrict__ B0,
    float* __restrict__ out, int N) {
  __shared__ float wr_s[288], wm_s[288];
  __shared__ float Bsh[360];
  int t = threadIdx.x, n = blockIdx.x;
  for (int i = t; i < 256; i += 192) {
    int d = i >> 6, rm = i & 63;
    wr_s[d*72+rm] = Wrad[i];
    wm_s[d*72+rm] = Wmem[i];
  }
  for (int i = t; i < 360; i += 192) Bsh[i] = 0.0f;
  int l = t / 9, c = t - l*9;
  bool act = t < 180;
  int ll = act ? l : 0, cc = act ? c : 0;
  int tt = act ? t : 0;
  size_t plane = (size_t)N * 180;
  float Sacc[8], ARacc[8];
  #pragma unroll
  for (int r = 0; r < 8; r++) { Sacc[r] = 0.0f; ARacc[r] = 0.0f; }
  int start = offs[n], end = offs[n+1];
  #pragma unroll 4
  for (int j = start; j < end; j++) {
    const float* row = edata + (size_t)j * 48;      // SEQUENTIAL
    int snd = esend[j];                             // SEQUENTIAL s_load
    float ch = chi[snd*9 + cc];                     // depth-1 gather
    float pch = row[16+ll] * row[36+cc] * ch;
    #pragma unroll
    for (int r = 0; r < 8; r++) Sacc[r] += row[r] * pch;
    const unsigned int* gp = Abf2 + (size_t)snd*180 + tt;   // depth-1, 4B/lane
    unsigned int q0 = gp[0];
    unsigned int q1 = gp[plane];
    unsigned int q2 = gp[2*plane];
    unsigned int q3 = gp[3*plane];
    float a0 = __uint_as_float(q0 << 16), a1 = __uint_as_float(q0 & 0xffff0000u);
    float a2 = __uint_as_float(q1 << 16), a3 = __uint_as_float(q1 & 0xffff0000u);
    float a4 = __uint_as_float(q2 << 16), a5 = __uint_as_float(q2 & 0xffff0000u);
    float a6 = __uint_as_float(q3 << 16), a7 = __uint_as_float(q3 & 0xffff0000u);
    ARacc[0] += a0*row[8];  ARacc[1] += a1*row[9];
    ARacc[2] += a2*row[10]; ARacc[3] += a3*row[11];
    ARacc[4] += a4*row[12]; ARacc[5] += a5*row[13];
    ARacc[6] += a6*row[14]; ARacc[7] += a7*row[15];
  }
  __syncthreads();   // weights/Bsh zeros visible
  if (act) {
    int deg = d_DEGS[ll];
    const float* wrp = &wr_s[deg*72];
    const float* wmp = &wm_s[deg*72];
    const float* aop = A + (size_t)n*1440 + t*8;
    float aown[8];
    #pragma unroll
    for (int r = 0; r < 8; r++) aown[r] = aop[r];
    float newA[8];
    #pragma unroll
    for (int b = 0; b < 8; b++) {
      float mem = 0.0f, ab = 0.0f;
      #pragma unroll
      for (int r = 0; r < 8; r++) { mem += aown[r]*wmp[r*8+b]; ab += Sacc[r]*wrp[r*8+b]; }
      newA[b] = (ARacc[b] + ab)*MPNORM + mem;
    }
    if (l == 0) {
      #pragma unroll
      for (int b = 0; b < 8; b++) Bsh[b*45 + c] = newA[b];
    }
    float mlt = d_MULTI[ll]; int kk = 1 + deg;
    #pragma unroll
    for (int b = 0; b < 8; b++) atomicAdd(&Bsh[b*45 + kk*9 + c], mlt*newA[b]*newA[b]);
  }
  __syncthreads();
  float2* out2 = reinterpret_cast<float2*>(out);
  for (int i = t; i < 360; i += 192) {
    float2 pk; pk.x = B0[(size_t)n*360 + i]; pk.y = Bsh[i];
    out2[(size_t)n*360 + i] = pk;            // coalesced 8B stores
  }
}

extern "C" void kernel_launch(void* const* d_in, const int* in_sizes, int n_in,
                              void* d_out, int out_size, void* d_ws, size_t ws_size,
                              hipStream_t stream) {
  const float* pos    = (const float*)d_in[0];
  const float* shifts = (const float*)d_in[1];
  const float* Wemb   = (const float*)d_in[2];
  const float* Wrad   = (const float*)d_in[3];
  const float* Wmem   = (const float*)d_in[4];
  const float* War    = (const float*)d_in[5];
  const float* Wchi   = (const float*)d_in[6];
  const int* species = (const int*)d_in[7];
  const int* eidx    = (const int*)d_in[8];
  float* out = (float*)d_out;
  int N = in_sizes[7];
  int E = in_sizes[8] / 2;

  char* base = (char*)d_ws;
  size_t off = 0;
  float* edata = (float*)(base + off); off += (size_t)E*48*4;          // 9.6 MB (CSR-sorted)
  float* A     = (float*)(base + off); off += (size_t)N*1440*4;        // 11.52 MB
  unsigned int* Abf2 = (unsigned int*)(base + off); off += (size_t)N*180*4*4; // 5.76 MB
  float* chi   = (float*)(base + off); off += (size_t)N*9*4;
  float* B0    = (float*)(base + off); off += (size_t)N*360*4;         // 2.88 MB
  int* counts  = (int*)(base + off);   off += (size_t)N*4;
  int* cursor  = (int*)(base + off);   off += (size_t)N*4;
  int* offs    = (int*)(base + off);   off += (((size_t)(N+1)*4) + 15) & ~(size_t)15;
  int* esend   = (int*)(base + off);   off += (size_t)E*4;

  hipMemsetAsync(counts, 0, (size_t)N*2*4, stream);  // counts + cursor (adjacent)
  int eb = (E + 255) / 256;
  k_count<<<eb, 256, 0, stream>>>(eidx, counts, E);
  k_scan<<<1, 256, 0, stream>>>(counts, offs, N);
  k_edge<<<eb, 256, 0, stream>>>(pos, shifts, Wemb, War, species, eidx, offs, cursor,
                                 edata, esend, E);
  k_nodeA<<<N, 192, 0, stream>>>(edata, offs, Wrad, Wchi, A, Abf2, chi, B0, N);
  k_node2<<<N, 192, 0, stream>>>(edata, esend, offs, Wrad, Wmem, A, Abf2, chi, B0, out, N);
}